// Round 1
// baseline (927.597 us; speedup 1.0000x reference)
//
#include <hip/hip_runtime.h>
#include <cstddef>

#define NN   100000
#define EE   3200000
#define GG   512
#define NPAD 100032   // 1563 * 64, row padding for the GEMM grid

typedef __attribute__((ext_vector_type(8))) short bf16x8;
typedef __attribute__((ext_vector_type(4))) float f32x4;

static __device__ __forceinline__ unsigned short f2b(float f) {
  unsigned u = __float_as_uint(f);
  unsigned r = u + 0x7fffu + ((u >> 16) & 1u);   // RNE
  return (unsigned short)(r >> 16);
}
static __device__ __forceinline__ float b2f(unsigned short s) {
  return __uint_as_float(((unsigned)s) << 16);
}

// ---------------- degree count (int atomics) ----------------
__global__ void k_deg(const int* __restrict__ src, int* __restrict__ deg) {
  int e = blockIdx.x * 256 + threadIdx.x;
  if (e < EE) atomicAdd(&deg[src[e]], 1);
}

// ---------------- prefix scan (3 stages) ----------------
__global__ void k_scan1(const int* __restrict__ deg, int* __restrict__ bsum) {
  __shared__ int sh[256];
  int i = blockIdx.x * 256 + threadIdx.x;
  int v = (i < NN) ? deg[i] : 0;
  sh[threadIdx.x] = v; __syncthreads();
  for (int s = 128; s > 0; s >>= 1) {
    if (threadIdx.x < s) sh[threadIdx.x] += sh[threadIdx.x + s];
    __syncthreads();
  }
  if (threadIdx.x == 0) bsum[blockIdx.x] = sh[0];
}

__global__ void k_scan2(int* __restrict__ bsum, int nb) {
  __shared__ int sh[512];
  int t = threadIdx.x;
  int v0 = (t < nb) ? bsum[t] : 0;
  sh[t] = v0; __syncthreads();
  for (int s = 1; s < 512; s <<= 1) {
    int a = (t >= s) ? sh[t - s] : 0;
    __syncthreads();
    sh[t] += a;
    __syncthreads();
  }
  if (t < nb) bsum[t] = sh[t] - v0;   // exclusive
}

__global__ void k_scan3(const int* __restrict__ deg, const int* __restrict__ bsum,
                        int* __restrict__ row_off, int* __restrict__ cursor,
                        float* __restrict__ nrm) {
  __shared__ int sh[256];
  int t = threadIdx.x, i = blockIdx.x * 256 + t;
  int v = (i < NN) ? deg[i] : 0;
  sh[t] = v; __syncthreads();
  for (int s = 1; s < 256; s <<= 1) {
    int a = (t >= s) ? sh[t - s] : 0;
    __syncthreads();
    sh[t] += a;
    __syncthreads();
  }
  int excl = sh[t] - v + bsum[blockIdx.x];
  if (i < NN) {
    row_off[i] = excl;
    cursor[i]  = excl;
    nrm[i] = rsqrtf((float)v);        // deg==0 -> +inf, matches deg**-0.5
    if (i == NN - 1) row_off[NN] = excl + v;
  }
}

// ---------------- CSR scatter ----------------
__global__ void k_scatter(const int* __restrict__ src, const int* __restrict__ dst,
                          int* __restrict__ cursor, int* __restrict__ csr) {
  int e = blockIdx.x * 256 + threadIdx.x;
  if (e < EE) {
    int s = src[e];
    int slot = atomicAdd(&cursor[s], 1);
    csr[slot] = dst[e];
  }
}

// ---------------- fp32 -> bf16 conversions ----------------
__global__ void k_cvt_x(const float* __restrict__ x, unsigned short* __restrict__ xbf) {
  int i = blockIdx.x * 256 + threadIdx.x;   // one float4 per thread, NN*64 total
  float4 v = ((const float4*)x)[i];
  ushort4 o;
  o.x = f2b(v.x); o.y = f2b(v.y); o.z = f2b(v.z); o.w = f2b(v.w);
  ((ushort4*)xbf)[i] = o;
}

__global__ void k_cvt_w(const float* __restrict__ w, unsigned short* __restrict__ wbf) {
  int i = blockIdx.x * 256 + threadIdx.x;   // 16384 quads
  float4 v = ((const float4*)w)[i];
  ushort4 o;
  o.x = f2b(v.x); o.y = f2b(v.y); o.z = f2b(v.z); o.w = f2b(v.w);
  ((ushort4*)wbf)[i] = o;
}

// ---------------- graph boundaries (batch is sorted) ----------------
__global__ void k_bounds(const int* __restrict__ batch, int* __restrict__ gs,
                         int* __restrict__ ge) {
  int i = blockIdx.x * 256 + threadIdx.x;
  if (i >= NN) return;
  int b = batch[i];
  if (i == 0 || batch[i - 1] != b) gs[b] = i;
  if (i == NN - 1 || batch[i + 1] != b) ge[b] = i + 1;
}

// ---------------- aggregation: one wave per node, bf16 gather ----------------
__global__ __launch_bounds__(256) void k_agg(const unsigned short* __restrict__ xbf,
                                             const int* __restrict__ row_off,
                                             const int* __restrict__ csr,
                                             const float* __restrict__ nrm,
                                             unsigned short* __restrict__ aggb) {
  const int wave = threadIdx.x >> 6;
  const int lane = threadIdx.x & 63;
  const int i = blockIdx.x * 4 + wave;
  if (i >= NN) return;

  const float ni = nrm[i];
  int e0 = __builtin_amdgcn_readfirstlane(row_off[i]);
  int e1 = __builtin_amdgcn_readfirstlane(row_off[i + 1]);

  const ushort4* __restrict__ xr = (const ushort4*)xbf;  // row = 64 x ushort4

  // self-loop term: (norm*norm) * x[i]
  ushort4 sv = xr[(size_t)i * 64 + lane];
  float cs = ni * ni;
  float a0 = cs * b2f(sv.x), a1 = cs * b2f(sv.y), a2 = cs * b2f(sv.z), a3 = cs * b2f(sv.w);

  int e = e0;
  for (; e + 4 <= e1; e += 4) {
    int d0 = csr[e], d1 = csr[e + 1], d2 = csr[e + 2], d3 = csr[e + 3];
    float c0 = ni * nrm[d0], c1 = ni * nrm[d1], c2 = ni * nrm[d2], c3 = ni * nrm[d3];
    ushort4 v0 = xr[(size_t)d0 * 64 + lane];
    ushort4 v1 = xr[(size_t)d1 * 64 + lane];
    ushort4 v2 = xr[(size_t)d2 * 64 + lane];
    ushort4 v3 = xr[(size_t)d3 * 64 + lane];
    a0 += c0 * b2f(v0.x) + c1 * b2f(v1.x) + c2 * b2f(v2.x) + c3 * b2f(v3.x);
    a1 += c0 * b2f(v0.y) + c1 * b2f(v1.y) + c2 * b2f(v2.y) + c3 * b2f(v3.y);
    a2 += c0 * b2f(v0.z) + c1 * b2f(v1.z) + c2 * b2f(v2.z) + c3 * b2f(v3.z);
    a3 += c0 * b2f(v0.w) + c1 * b2f(v1.w) + c2 * b2f(v2.w) + c3 * b2f(v3.w);
  }
  for (; e < e1; ++e) {
    int d = csr[e];
    float cc = ni * nrm[d];
    ushort4 v = xr[(size_t)d * 64 + lane];
    a0 += cc * b2f(v.x); a1 += cc * b2f(v.y); a2 += cc * b2f(v.z); a3 += cc * b2f(v.w);
  }

  ushort4 o;
  o.x = f2b(a0); o.y = f2b(a1); o.z = f2b(a2); o.w = f2b(a3);
  ((ushort4*)aggb)[(size_t)i * 64 + lane] = o;
}

// ---------------- h = relu(agg @ W1^T + b1), bf16 MFMA ----------------
// wave computes 16 rows x 256 cols; block of 4 waves = 64 rows.
__global__ __launch_bounds__(256) void k_gemm(const unsigned short* __restrict__ aggb,
                                              const unsigned short* __restrict__ wbf,
                                              const float* __restrict__ b1,
                                              unsigned short* __restrict__ hout) {
  const int wave = threadIdx.x >> 6;
  const int lane = threadIdx.x & 63;
  const int r16  = lane & 15;   // A row / B col(n)
  const int quad = lane >> 4;   // k-group
  const size_t m0 = (size_t)blockIdx.x * 64 + (size_t)wave * 16;

  f32x4 acc[16];
#pragma unroll
  for (int t = 0; t < 16; ++t) acc[t] = (f32x4){0.f, 0.f, 0.f, 0.f};

  const unsigned short* arow = aggb + (m0 + (size_t)r16) * 256 + quad * 8;
  for (int kc = 0; kc < 8; ++kc) {
    bf16x8 af = *(const bf16x8*)(arow + kc * 32);
#pragma unroll
    for (int t = 0; t < 16; ++t) {
      bf16x8 bf = *(const bf16x8*)(wbf + (size_t)(t * 16 + r16) * 256 + kc * 32 + quad * 8);
      acc[t] = __builtin_amdgcn_mfma_f32_16x16x32_bf16(af, bf, acc[t], 0, 0, 0);
    }
  }

  const size_t orow = m0 + (size_t)quad * 4;
#pragma unroll
  for (int t = 0; t < 16; ++t) {
    const int col = t * 16 + r16;
    const float bias = b1[col];
#pragma unroll
    for (int r = 0; r < 4; ++r) {
      float v = fmaxf(acc[t][r] + bias, 0.f);
      hout[(orow + r) * 256 + col] = f2b(v);
    }
  }
}

// ---------------- segment-max pool ----------------
__global__ void k_pool(const unsigned short* __restrict__ h, const int* __restrict__ gs,
                       const int* __restrict__ ge, float* __restrict__ pooled) {
  const int g = blockIdx.x, t = threadIdx.x;
  int r = gs[g];
  const int r1 = ge[g];
  float m = 0.f;   // h >= 0 post-ReLU
  for (; r + 4 <= r1; r += 4) {
    float v0 = b2f(h[(size_t)r * 256 + t]);
    float v1 = b2f(h[(size_t)(r + 1) * 256 + t]);
    float v2 = b2f(h[(size_t)(r + 2) * 256 + t]);
    float v3 = b2f(h[(size_t)(r + 3) * 256 + t]);
    m = fmaxf(m, fmaxf(fmaxf(v0, v1), fmaxf(v2, v3)));
  }
  for (; r < r1; ++r) m = fmaxf(m, b2f(h[(size_t)r * 256 + t]));
  pooled[g * 256 + t] = m;
}

// ---------------- out = pooled @ W2^T + b2 ----------------
__global__ void k_out(const float* __restrict__ pooled, const float* __restrict__ w2,
                      const float* __restrict__ b2, float* __restrict__ out) {
  const int wave = threadIdx.x >> 6;
  const int lane = threadIdx.x & 63;
  const int g = blockIdx.x * 4 + wave;
  float4 p = ((const float4*)pooled)[g * 64 + lane];
  float4 w = ((const float4*)w2)[lane];
  float s = p.x * w.x + p.y * w.y + p.z * w.z + p.w * w.w;
  for (int off = 32; off; off >>= 1) s += __shfl_down(s, off, 64);
  if (lane == 0) out[g] = s + b2[0];
}

extern "C" void kernel_launch(void* const* d_in, const int* in_sizes, int n_in,
                              void* d_out, int out_size, void* d_ws, size_t ws_size,
                              hipStream_t stream) {
  const float* x     = (const float*)d_in[0];
  const int*   ei    = (const int*)d_in[1];
  const int*   batch = (const int*)d_in[2];
  const float* W1    = (const float*)d_in[3];
  const float* b1    = (const float*)d_in[4];
  const float* W2    = (const float*)d_in[5];
  const float* b2    = (const float*)d_in[6];
  const int* src = ei;
  const int* dst = ei + EE;
  float* out = (float*)d_out;

  // workspace carve (256B aligned)
  size_t off = 0;
  auto carve = [&](size_t bytes) -> void* {
    void* p = (char*)d_ws + off;
    off += (bytes + 255) & ~(size_t)255;
    return p;
  };
  unsigned short* xbf  = (unsigned short*)carve((size_t)NPAD * 256 * 2); // also h (reused)
  unsigned short* aggb = (unsigned short*)carve((size_t)NPAD * 256 * 2);
  int*   csr     = (int*)carve((size_t)EE * 4);
  int*   deg     = (int*)carve((size_t)NN * 4);
  int*   row_off = (int*)carve((size_t)(NN + 1) * 4);
  int*   cursor  = (int*)carve((size_t)NN * 4);
  float* nrm     = (float*)carve((size_t)NN * 4);
  int*   bsum    = (int*)carve(512 * 4);
  int*   gse     = (int*)carve((size_t)2 * GG * 4);   // gstart | gend
  float* pooled  = (float*)carve((size_t)GG * 256 * 4);
  unsigned short* wbf = (unsigned short*)carve(256 * 256 * 2);
  int* gs = gse;
  int* ge = gse + GG;

  const int NB = (NN + 255) / 256;   // 391

  hipMemsetAsync(deg, 0, (size_t)NN * 4, stream);
  hipMemsetAsync(gse, 0, (size_t)2 * GG * 4, stream);

  k_cvt_x  <<<NN * 64 / 256, 256, 0, stream>>>(x, xbf);
  k_cvt_w  <<<64, 256, 0, stream>>>(W1, wbf);
  k_deg    <<<EE / 256, 256, 0, stream>>>(src, deg);
  k_bounds <<<NB, 256, 0, stream>>>(batch, gs, ge);
  k_scan1  <<<NB, 256, 0, stream>>>(deg, bsum);
  k_scan2  <<<1, 512, 0, stream>>>(bsum, NB);
  k_scan3  <<<NB, 256, 0, stream>>>(deg, bsum, row_off, cursor, nrm);
  k_scatter<<<EE / 256, 256, 0, stream>>>(src, dst, cursor, csr);
  k_agg    <<<(NN + 3) / 4, 256, 0, stream>>>(xbf, row_off, csr, nrm, aggb);
  k_gemm   <<<NPAD / 64, 256, 0, stream>>>(aggb, wbf, b1, xbf /* h overwrites xbf */);
  k_pool   <<<GG, 256, 0, stream>>>(xbf, gs, ge, pooled);
  k_out    <<<GG / 4, 256, 0, stream>>>(pooled, W2, b2, out);
}

// Round 2
// 865.281 us; speedup vs baseline: 1.0720x; 1.0720x over previous
//
#include <hip/hip_runtime.h>
#include <cstddef>

#define NN   100000
#define EE   3200000
#define GG   512
#define NPAD 100032   // 1563 * 64, row padding for the GEMM grid
#define NPASS 8       // scatter passes; each writes a ~1.6MB L2-resident csr slice

typedef __attribute__((ext_vector_type(8))) short bf16x8;
typedef __attribute__((ext_vector_type(4))) float f32x4;

static __device__ __forceinline__ unsigned short f2b(float f) {
  unsigned u = __float_as_uint(f);
  unsigned r = u + 0x7fffu + ((u >> 16) & 1u);   // RNE
  return (unsigned short)(r >> 16);
}
static __device__ __forceinline__ float b2f(unsigned short s) {
  return __uint_as_float(((unsigned)s) << 16);
}

// ---------------- degree count (int atomics) ----------------
__global__ void k_deg(const int* __restrict__ src, int* __restrict__ deg) {
  int e = blockIdx.x * 256 + threadIdx.x;
  if (e < EE) atomicAdd(&deg[src[e]], 1);
}

// ---------------- prefix scan (3 stages) ----------------
__global__ void k_scan1(const int* __restrict__ deg, int* __restrict__ bsum) {
  __shared__ int sh[256];
  int i = blockIdx.x * 256 + threadIdx.x;
  int v = (i < NN) ? deg[i] : 0;
  sh[threadIdx.x] = v; __syncthreads();
  for (int s = 128; s > 0; s >>= 1) {
    if (threadIdx.x < s) sh[threadIdx.x] += sh[threadIdx.x + s];
    __syncthreads();
  }
  if (threadIdx.x == 0) bsum[blockIdx.x] = sh[0];
}

__global__ void k_scan2(int* __restrict__ bsum, int nb) {
  __shared__ int sh[512];
  int t = threadIdx.x;
  int v0 = (t < nb) ? bsum[t] : 0;
  sh[t] = v0; __syncthreads();
  for (int s = 1; s < 512; s <<= 1) {
    int a = (t >= s) ? sh[t - s] : 0;
    __syncthreads();
    sh[t] += a;
    __syncthreads();
  }
  if (t < nb) bsum[t] = sh[t] - v0;   // exclusive
}

__global__ void k_scan3(const int* __restrict__ deg, const int* __restrict__ bsum,
                        int* __restrict__ row_off, int* __restrict__ cursor,
                        float* __restrict__ nrm) {
  __shared__ int sh[256];
  int t = threadIdx.x, i = blockIdx.x * 256 + t;
  int v = (i < NN) ? deg[i] : 0;
  sh[t] = v; __syncthreads();
  for (int s = 1; s < 256; s <<= 1) {
    int a = (t >= s) ? sh[t - s] : 0;
    __syncthreads();
    sh[t] += a;
    __syncthreads();
  }
  int excl = sh[t] - v + bsum[blockIdx.x];
  if (i < NN) {
    row_off[i] = excl;
    cursor[i]  = excl;
    nrm[i] = rsqrtf((float)v);        // deg==0 -> +inf, matches deg**-0.5
    if (i == NN - 1) row_off[NN] = excl + v;
  }
}

// ---------------- CSR scatter, src-range partitioned ----------------
// Pass writes only src in [lo,hi) -> csr slots [row_off[lo], row_off[hi])
// (~1.6MB with NPASS=8), which stays L2-resident so slot writes coalesce
// into full lines before writeback.
__global__ void k_scatter(const int* __restrict__ src, const int* __restrict__ dst,
                          int* __restrict__ cursor, int* __restrict__ csr,
                          int lo, int hi) {
  int e = blockIdx.x * 256 + threadIdx.x;
  if (e < EE) {
    int s = src[e];
    if (s >= lo && s < hi) {
      int slot = atomicAdd(&cursor[s], 1);
      csr[slot] = dst[e];
    }
  }
}

// ---------------- fp32 -> bf16 conversions ----------------
__global__ void k_cvt_x(const float* __restrict__ x, unsigned short* __restrict__ xbf) {
  int i = blockIdx.x * 256 + threadIdx.x;   // one float4 per thread, NN*64 total
  float4 v = ((const float4*)x)[i];
  ushort4 o;
  o.x = f2b(v.x); o.y = f2b(v.y); o.z = f2b(v.z); o.w = f2b(v.w);
  ((ushort4*)xbf)[i] = o;
}

__global__ void k_cvt_w(const float* __restrict__ w, unsigned short* __restrict__ wbf) {
  int i = blockIdx.x * 256 + threadIdx.x;   // 16384 quads
  float4 v = ((const float4*)w)[i];
  ushort4 o;
  o.x = f2b(v.x); o.y = f2b(v.y); o.z = f2b(v.z); o.w = f2b(v.w);
  ((ushort4*)wbf)[i] = o;
}

// ---------------- graph boundaries (batch is sorted) ----------------
__global__ void k_bounds(const int* __restrict__ batch, int* __restrict__ gs,
                         int* __restrict__ ge) {
  int i = blockIdx.x * 256 + threadIdx.x;
  if (i >= NN) return;
  int b = batch[i];
  if (i == 0 || batch[i - 1] != b) gs[b] = i;
  if (i == NN - 1 || batch[i + 1] != b) ge[b] = i + 1;
}

// ---------------- aggregation: one wave per node, bf16 gather ----------------
__global__ __launch_bounds__(256) void k_agg(const unsigned short* __restrict__ xbf,
                                             const int* __restrict__ row_off,
                                             const int* __restrict__ csr,
                                             const float* __restrict__ nrm,
                                             unsigned short* __restrict__ aggb) {
  const int wave = threadIdx.x >> 6;
  const int lane = threadIdx.x & 63;
  const int i = blockIdx.x * 4 + wave;
  if (i >= NN) return;

  const float ni = nrm[i];
  int e0 = __builtin_amdgcn_readfirstlane(row_off[i]);
  int e1 = __builtin_amdgcn_readfirstlane(row_off[i + 1]);

  const ushort4* __restrict__ xr = (const ushort4*)xbf;  // row = 64 x ushort4

  // self-loop term: (norm*norm) * x[i]
  ushort4 sv = xr[(size_t)i * 64 + lane];
  float cs = ni * ni;
  float a0 = cs * b2f(sv.x), a1 = cs * b2f(sv.y), a2 = cs * b2f(sv.z), a3 = cs * b2f(sv.w);

  int e = e0;
  for (; e + 4 <= e1; e += 4) {
    int d0 = csr[e], d1 = csr[e + 1], d2 = csr[e + 2], d3 = csr[e + 3];
    float c0 = ni * nrm[d0], c1 = ni * nrm[d1], c2 = ni * nrm[d2], c3 = ni * nrm[d3];
    ushort4 v0 = xr[(size_t)d0 * 64 + lane];
    ushort4 v1 = xr[(size_t)d1 * 64 + lane];
    ushort4 v2 = xr[(size_t)d2 * 64 + lane];
    ushort4 v3 = xr[(size_t)d3 * 64 + lane];
    a0 += c0 * b2f(v0.x) + c1 * b2f(v1.x) + c2 * b2f(v2.x) + c3 * b2f(v3.x);
    a1 += c0 * b2f(v0.y) + c1 * b2f(v1.y) + c2 * b2f(v2.y) + c3 * b2f(v3.y);
    a2 += c0 * b2f(v0.z) + c1 * b2f(v1.z) + c2 * b2f(v2.z) + c3 * b2f(v3.z);
    a3 += c0 * b2f(v0.w) + c1 * b2f(v1.w) + c2 * b2f(v2.w) + c3 * b2f(v3.w);
  }
  for (; e < e1; ++e) {
    int d = csr[e];
    float cc = ni * nrm[d];
    ushort4 v = xr[(size_t)d * 64 + lane];
    a0 += cc * b2f(v.x); a1 += cc * b2f(v.y); a2 += cc * b2f(v.z); a3 += cc * b2f(v.w);
  }

  ushort4 o;
  o.x = f2b(a0); o.y = f2b(a1); o.z = f2b(a2); o.w = f2b(a3);
  ((ushort4*)aggb)[(size_t)i * 64 + lane] = o;
}

// ---------------- h = relu(agg @ W1^T + b1), bf16 MFMA ----------------
// wave computes 16 rows x 256 cols; block of 4 waves = 64 rows.
__global__ __launch_bounds__(256) void k_gemm(const unsigned short* __restrict__ aggb,
                                              const unsigned short* __restrict__ wbf,
                                              const float* __restrict__ b1,
                                              unsigned short* __restrict__ hout) {
  const int wave = threadIdx.x >> 6;
  const int lane = threadIdx.x & 63;
  const int r16  = lane & 15;   // A row / B col(n)
  const int quad = lane >> 4;   // k-group
  const size_t m0 = (size_t)blockIdx.x * 64 + (size_t)wave * 16;

  f32x4 acc[16];
#pragma unroll
  for (int t = 0; t < 16; ++t) acc[t] = (f32x4){0.f, 0.f, 0.f, 0.f};

  const unsigned short* arow = aggb + (m0 + (size_t)r16) * 256 + quad * 8;
  for (int kc = 0; kc < 8; ++kc) {
    bf16x8 af = *(const bf16x8*)(arow + kc * 32);
#pragma unroll
    for (int t = 0; t < 16; ++t) {
      bf16x8 bf = *(const bf16x8*)(wbf + (size_t)(t * 16 + r16) * 256 + kc * 32 + quad * 8);
      acc[t] = __builtin_amdgcn_mfma_f32_16x16x32_bf16(af, bf, acc[t], 0, 0, 0);
    }
  }

  const size_t orow = m0 + (size_t)quad * 4;
#pragma unroll
  for (int t = 0; t < 16; ++t) {
    const int col = t * 16 + r16;
    const float bias = b1[col];
#pragma unroll
    for (int r = 0; r < 4; ++r) {
      float v = fmaxf(acc[t][r] + bias, 0.f);
      hout[(orow + r) * 256 + col] = f2b(v);
    }
  }
}

// ---------------- segment-max pool ----------------
__global__ void k_pool(const unsigned short* __restrict__ h, const int* __restrict__ gs,
                       const int* __restrict__ ge, float* __restrict__ pooled) {
  const int g = blockIdx.x, t = threadIdx.x;
  int r = gs[g];
  const int r1 = ge[g];
  float m = 0.f;   // h >= 0 post-ReLU
  for (; r + 4 <= r1; r += 4) {
    float v0 = b2f(h[(size_t)r * 256 + t]);
    float v1 = b2f(h[(size_t)(r + 1) * 256 + t]);
    float v2 = b2f(h[(size_t)(r + 2) * 256 + t]);
    float v3 = b2f(h[(size_t)(r + 3) * 256 + t]);
    m = fmaxf(m, fmaxf(fmaxf(v0, v1), fmaxf(v2, v3)));
  }
  for (; r < r1; ++r) m = fmaxf(m, b2f(h[(size_t)r * 256 + t]));
  pooled[g * 256 + t] = m;
}

// ---------------- out = pooled @ W2^T + b2 ----------------
__global__ void k_out(const float* __restrict__ pooled, const float* __restrict__ w2,
                      const float* __restrict__ b2, float* __restrict__ out) {
  const int wave = threadIdx.x >> 6;
  const int lane = threadIdx.x & 63;
  const int g = blockIdx.x * 4 + wave;
  float4 p = ((const float4*)pooled)[g * 64 + lane];
  float4 w = ((const float4*)w2)[lane];
  float s = p.x * w.x + p.y * w.y + p.z * w.z + p.w * w.w;
  for (int off = 32; off; off >>= 1) s += __shfl_down(s, off, 64);
  if (lane == 0) out[g] = s + b2[0];
}

extern "C" void kernel_launch(void* const* d_in, const int* in_sizes, int n_in,
                              void* d_out, int out_size, void* d_ws, size_t ws_size,
                              hipStream_t stream) {
  const float* x     = (const float*)d_in[0];
  const int*   ei    = (const int*)d_in[1];
  const int*   batch = (const int*)d_in[2];
  const float* W1    = (const float*)d_in[3];
  const float* b1    = (const float*)d_in[4];
  const float* W2    = (const float*)d_in[5];
  const float* b2    = (const float*)d_in[6];
  const int* src = ei;
  const int* dst = ei + EE;
  float* out = (float*)d_out;

  // workspace carve (256B aligned)
  size_t off = 0;
  auto carve = [&](size_t bytes) -> void* {
    void* p = (char*)d_ws + off;
    off += (bytes + 255) & ~(size_t)255;
    return p;
  };
  unsigned short* xbf  = (unsigned short*)carve((size_t)NPAD * 256 * 2); // also h (reused)
  unsigned short* aggb = (unsigned short*)carve((size_t)NPAD * 256 * 2);
  int*   csr     = (int*)carve((size_t)EE * 4);
  int*   deg     = (int*)carve((size_t)NN * 4);
  int*   row_off = (int*)carve((size_t)(NN + 1) * 4);
  int*   cursor  = (int*)carve((size_t)NN * 4);
  float* nrm     = (float*)carve((size_t)NN * 4);
  int*   bsum    = (int*)carve(512 * 4);
  int*   gse     = (int*)carve((size_t)2 * GG * 4);   // gstart | gend
  float* pooled  = (float*)carve((size_t)GG * 256 * 4);
  unsigned short* wbf = (unsigned short*)carve(256 * 256 * 2);
  int* gs = gse;
  int* ge = gse + GG;

  const int NB = (NN + 255) / 256;   // 391

  hipMemsetAsync(deg, 0, (size_t)NN * 4, stream);
  hipMemsetAsync(gse, 0, (size_t)2 * GG * 4, stream);

  k_cvt_x  <<<NN * 64 / 256, 256, 0, stream>>>(x, xbf);
  k_cvt_w  <<<64, 256, 0, stream>>>(W1, wbf);
  k_deg    <<<EE / 256, 256, 0, stream>>>(src, deg);
  k_bounds <<<NB, 256, 0, stream>>>(batch, gs, ge);
  k_scan1  <<<NB, 256, 0, stream>>>(deg, bsum);
  k_scan2  <<<1, 512, 0, stream>>>(bsum, NB);
  k_scan3  <<<NB, 256, 0, stream>>>(deg, bsum, row_off, cursor, nrm);

  // 8 sequential src-range passes: each pass's csr slice (~1.6MB) stays
  // L2-resident so the 16 slot-writes per 64B line coalesce before writeback.
  const int span = (NN + NPASS - 1) / NPASS;   // 12500
  for (int p = 0; p < NPASS; ++p) {
    int lo = p * span;
    int hi = (lo + span < NN) ? lo + span : NN;
    k_scatter<<<EE / 256, 256, 0, stream>>>(src, dst, cursor, csr, lo, hi);
  }

  k_agg    <<<(NN + 3) / 4, 256, 0, stream>>>(xbf, row_off, csr, nrm, aggb);
  k_gemm   <<<NPAD / 64, 256, 0, stream>>>(aggb, wbf, b1, xbf /* h overwrites xbf */);
  k_pool   <<<GG, 256, 0, stream>>>(xbf, gs, ge, pooled);
  k_out    <<<GG / 4, 256, 0, stream>>>(pooled, W2, b2, out);
}

// Round 3
// 851.915 us; speedup vs baseline: 1.0888x; 1.0157x over previous
//
#include <hip/hip_runtime.h>
#include <cstddef>

#define NN   100000
#define EE   3200000
#define GG   512
#define NPAD 100032   // 1563 * 64, row padding for the GEMM grid
#define NPASS 5       // scatter passes; each writes a ~2.6MB L2-resident csr slice

typedef __attribute__((ext_vector_type(8))) short bf16x8;
typedef __attribute__((ext_vector_type(4))) float f32x4;
typedef __attribute__((ext_vector_type(8))) unsigned short u16x8;

static __device__ __forceinline__ unsigned short f2b(float f) {
  unsigned u = __float_as_uint(f);
  unsigned r = u + 0x7fffu + ((u >> 16) & 1u);   // RNE
  return (unsigned short)(r >> 16);
}
static __device__ __forceinline__ float b2f(unsigned short s) {
  return __uint_as_float(((unsigned)s) << 16);
}

// ---------------- degree count (int atomics) ----------------
__global__ void k_deg(const int* __restrict__ src, int* __restrict__ deg) {
  int e = blockIdx.x * 256 + threadIdx.x;
  if (e < EE) atomicAdd(&deg[src[e]], 1);
}

// ---------------- prefix scan (3 stages) ----------------
__global__ void k_scan1(const int* __restrict__ deg, int* __restrict__ bsum) {
  __shared__ int sh[256];
  int i = blockIdx.x * 256 + threadIdx.x;
  int v = (i < NN) ? deg[i] : 0;
  sh[threadIdx.x] = v; __syncthreads();
  for (int s = 128; s > 0; s >>= 1) {
    if (threadIdx.x < s) sh[threadIdx.x] += sh[threadIdx.x + s];
    __syncthreads();
  }
  if (threadIdx.x == 0) bsum[blockIdx.x] = sh[0];
}

__global__ void k_scan2(int* __restrict__ bsum, int nb) {
  __shared__ int sh[512];
  int t = threadIdx.x;
  int v0 = (t < nb) ? bsum[t] : 0;
  sh[t] = v0; __syncthreads();
  for (int s = 1; s < 512; s <<= 1) {
    int a = (t >= s) ? sh[t - s] : 0;
    __syncthreads();
    sh[t] += a;
    __syncthreads();
  }
  if (t < nb) bsum[t] = sh[t] - v0;   // exclusive
}

__global__ void k_scan3(const int* __restrict__ deg, const int* __restrict__ bsum,
                        int* __restrict__ row_off, int* __restrict__ cursor,
                        float* __restrict__ nrm) {
  __shared__ int sh[256];
  int t = threadIdx.x, i = blockIdx.x * 256 + t;
  int v = (i < NN) ? deg[i] : 0;
  sh[t] = v; __syncthreads();
  for (int s = 1; s < 256; s <<= 1) {
    int a = (t >= s) ? sh[t - s] : 0;
    __syncthreads();
    sh[t] += a;
    __syncthreads();
  }
  int excl = sh[t] - v + bsum[blockIdx.x];
  if (i < NN) {
    row_off[i] = excl;
    cursor[i]  = excl;
    nrm[i] = rsqrtf((float)v);        // deg==0 -> +inf, matches deg**-0.5
    if (i == NN - 1) row_off[NN] = excl + v;
  }
}

// ---------------- CSR scatter, src-range partitioned ----------------
__global__ void k_scatter(const int* __restrict__ src, const int* __restrict__ dst,
                          int* __restrict__ cursor, int* __restrict__ csr,
                          int lo, int hi) {
  int e = blockIdx.x * 256 + threadIdx.x;
  if (e < EE) {
    int s = src[e];
    if (s >= lo && s < hi) {
      int slot = atomicAdd(&cursor[s], 1);
      csr[slot] = dst[e];
    }
  }
}

// ---------------- fp32 -> bf16 conversions ----------------
__global__ void k_cvt_x(const float* __restrict__ x, unsigned short* __restrict__ xbf) {
  int i = blockIdx.x * 256 + threadIdx.x;   // one float4 per thread, NN*64 total
  float4 v = ((const float4*)x)[i];
  ushort4 o;
  o.x = f2b(v.x); o.y = f2b(v.y); o.z = f2b(v.z); o.w = f2b(v.w);
  ((ushort4*)xbf)[i] = o;
}

__global__ void k_cvt_w(const float* __restrict__ w, unsigned short* __restrict__ wbf) {
  int i = blockIdx.x * 256 + threadIdx.x;   // 16384 quads
  float4 v = ((const float4*)w)[i];
  ushort4 o;
  o.x = f2b(v.x); o.y = f2b(v.y); o.z = f2b(v.z); o.w = f2b(v.w);
  ((ushort4*)wbf)[i] = o;
}

// ---------------- graph boundaries (batch is sorted) ----------------
__global__ void k_bounds(const int* __restrict__ batch, int* __restrict__ gs,
                         int* __restrict__ ge) {
  int i = blockIdx.x * 256 + threadIdx.x;
  if (i >= NN) return;
  int b = batch[i];
  if (i == 0 || batch[i - 1] != b) gs[b] = i;
  if (i == NN - 1 || batch[i + 1] != b) ge[b] = i + 1;
}

// ---------------- aggregation: half-wave per node, 16B/lane gather ----------------
// 2 nodes per wave (lanes 0-31 / 32-63); each half reads a 512B row as 32 x 16B.
// Halves load-instruction count vs 8B/lane and doubles edges in flight per wave.
__global__ __launch_bounds__(256) void k_agg(const unsigned short* __restrict__ xbf,
                                             const int* __restrict__ row_off,
                                             const int* __restrict__ csr,
                                             const float* __restrict__ nrm,
                                             unsigned short* __restrict__ aggb) {
  const int wave = threadIdx.x >> 6;
  const int lane = threadIdx.x & 63;
  const int half = lane >> 5;
  const int l32  = lane & 31;
  const int i = blockIdx.x * 8 + wave * 2 + half;   // 12500 blocks * 8 = 100000 exact

  const float ni = nrm[i];
  const int e0 = row_off[i];
  const int e1 = row_off[i + 1];

  const u16x8* __restrict__ xr = (const u16x8*)xbf;   // row = 32 x u16x8

  // self-loop term: (norm*norm) * x[i]
  u16x8 sv = xr[(size_t)i * 32 + l32];
  const float cs = ni * ni;
  float acc[8];
#pragma unroll
  for (int c = 0; c < 8; ++c) acc[c] = cs * b2f(sv[c]);

  int e = e0;
  for (; e + 4 <= e1; e += 4) {
    int d0 = csr[e], d1 = csr[e + 1], d2 = csr[e + 2], d3 = csr[e + 3];
    float c0 = ni * nrm[d0], c1 = ni * nrm[d1], c2 = ni * nrm[d2], c3 = ni * nrm[d3];
    u16x8 v0 = xr[(size_t)d0 * 32 + l32];
    u16x8 v1 = xr[(size_t)d1 * 32 + l32];
    u16x8 v2 = xr[(size_t)d2 * 32 + l32];
    u16x8 v3 = xr[(size_t)d3 * 32 + l32];
#pragma unroll
    for (int c = 0; c < 8; ++c)
      acc[c] += c0 * b2f(v0[c]) + c1 * b2f(v1[c]) + c2 * b2f(v2[c]) + c3 * b2f(v3[c]);
  }
  for (; e < e1; ++e) {
    int d = csr[e];
    float cc = ni * nrm[d];
    u16x8 v = xr[(size_t)d * 32 + l32];
#pragma unroll
    for (int c = 0; c < 8; ++c) acc[c] += cc * b2f(v[c]);
  }

  u16x8 o;
#pragma unroll
  for (int c = 0; c < 8; ++c) o[c] = f2b(acc[c]);
  ((u16x8*)aggb)[(size_t)i * 32 + l32] = o;
}

// ---------------- h = relu(agg @ W1^T + b1), bf16 MFMA ----------------
__global__ __launch_bounds__(256) void k_gemm(const unsigned short* __restrict__ aggb,
                                              const unsigned short* __restrict__ wbf,
                                              const float* __restrict__ b1,
                                              unsigned short* __restrict__ hout) {
  const int wave = threadIdx.x >> 6;
  const int lane = threadIdx.x & 63;
  const int r16  = lane & 15;   // A row / B col(n)
  const int quad = lane >> 4;   // k-group
  const size_t m0 = (size_t)blockIdx.x * 64 + (size_t)wave * 16;

  f32x4 acc[16];
#pragma unroll
  for (int t = 0; t < 16; ++t) acc[t] = (f32x4){0.f, 0.f, 0.f, 0.f};

  const unsigned short* arow = aggb + (m0 + (size_t)r16) * 256 + quad * 8;
  for (int kc = 0; kc < 8; ++kc) {
    bf16x8 af = *(const bf16x8*)(arow + kc * 32);
#pragma unroll
    for (int t = 0; t < 16; ++t) {
      bf16x8 bf = *(const bf16x8*)(wbf + (size_t)(t * 16 + r16) * 256 + kc * 32 + quad * 8);
      acc[t] = __builtin_amdgcn_mfma_f32_16x16x32_bf16(af, bf, acc[t], 0, 0, 0);
    }
  }

  const size_t orow = m0 + (size_t)quad * 4;
#pragma unroll
  for (int t = 0; t < 16; ++t) {
    const int col = t * 16 + r16;
    const float bias = b1[col];
#pragma unroll
    for (int r = 0; r < 4; ++r) {
      float v = fmaxf(acc[t][r] + bias, 0.f);
      hout[(orow + r) * 256 + col] = f2b(v);
    }
  }
}

// ---------------- segment-max pool ----------------
__global__ void k_pool(const unsigned short* __restrict__ h, const int* __restrict__ gs,
                       const int* __restrict__ ge, float* __restrict__ pooled) {
  const int g = blockIdx.x, t = threadIdx.x;
  int r = gs[g];
  const int r1 = ge[g];
  float m = 0.f;   // h >= 0 post-ReLU
  for (; r + 4 <= r1; r += 4) {
    float v0 = b2f(h[(size_t)r * 256 + t]);
    float v1 = b2f(h[(size_t)(r + 1) * 256 + t]);
    float v2 = b2f(h[(size_t)(r + 2) * 256 + t]);
    float v3 = b2f(h[(size_t)(r + 3) * 256 + t]);
    m = fmaxf(m, fmaxf(fmaxf(v0, v1), fmaxf(v2, v3)));
  }
  for (; r < r1; ++r) m = fmaxf(m, b2f(h[(size_t)r * 256 + t]));
  pooled[g * 256 + t] = m;
}

// ---------------- out = pooled @ W2^T + b2 ----------------
__global__ void k_out(const float* __restrict__ pooled, const float* __restrict__ w2,
                      const float* __restrict__ b2, float* __restrict__ out) {
  const int wave = threadIdx.x >> 6;
  const int lane = threadIdx.x & 63;
  const int g = blockIdx.x * 4 + wave;
  float4 p = ((const float4*)pooled)[g * 64 + lane];
  float4 w = ((const float4*)w2)[lane];
  float s = p.x * w.x + p.y * w.y + p.z * w.z + p.w * w.w;
  for (int off = 32; off; off >>= 1) s += __shfl_down(s, off, 64);
  if (lane == 0) out[g] = s + b2[0];
}

extern "C" void kernel_launch(void* const* d_in, const int* in_sizes, int n_in,
                              void* d_out, int out_size, void* d_ws, size_t ws_size,
                              hipStream_t stream) {
  const float* x     = (const float*)d_in[0];
  const int*   ei    = (const int*)d_in[1];
  const int*   batch = (const int*)d_in[2];
  const float* W1    = (const float*)d_in[3];
  const float* b1    = (const float*)d_in[4];
  const float* W2    = (const float*)d_in[5];
  const float* b2    = (const float*)d_in[6];
  const int* src = ei;
  const int* dst = ei + EE;
  float* out = (float*)d_out;

  // workspace carve (256B aligned)
  size_t off = 0;
  auto carve = [&](size_t bytes) -> void* {
    void* p = (char*)d_ws + off;
    off += (bytes + 255) & ~(size_t)255;
    return p;
  };
  unsigned short* xbf  = (unsigned short*)carve((size_t)NPAD * 256 * 2); // also h (reused)
  unsigned short* aggb = (unsigned short*)carve((size_t)NPAD * 256 * 2);
  int*   csr     = (int*)carve((size_t)EE * 4);
  int*   deg     = (int*)carve((size_t)NN * 4);
  int*   row_off = (int*)carve((size_t)(NN + 1) * 4);
  int*   cursor  = (int*)carve((size_t)NN * 4);
  float* nrm     = (float*)carve((size_t)NN * 4);
  int*   bsum    = (int*)carve(512 * 4);
  int*   gse     = (int*)carve((size_t)2 * GG * 4);   // gstart | gend
  float* pooled  = (float*)carve((size_t)GG * 256 * 4);
  unsigned short* wbf = (unsigned short*)carve(256 * 256 * 2);
  int* gs = gse;
  int* ge = gse + GG;

  const int NB = (NN + 255) / 256;   // 391

  hipMemsetAsync(deg, 0, (size_t)NN * 4, stream);
  hipMemsetAsync(gse, 0, (size_t)2 * GG * 4, stream);

  k_cvt_x  <<<NN * 64 / 256, 256, 0, stream>>>(x, xbf);
  k_cvt_w  <<<64, 256, 0, stream>>>(W1, wbf);
  k_deg    <<<EE / 256, 256, 0, stream>>>(src, deg);
  k_bounds <<<NB, 256, 0, stream>>>(batch, gs, ge);
  k_scan1  <<<NB, 256, 0, stream>>>(deg, bsum);
  k_scan2  <<<1, 512, 0, stream>>>(bsum, NB);
  k_scan3  <<<NB, 256, 0, stream>>>(deg, bsum, row_off, cursor, nrm);

  // src-range passes: each pass's csr slice (~2.6MB) stays L2-resident so the
  // 16 slot-writes per 64B line coalesce before writeback.
  const int span = (NN + NPASS - 1) / NPASS;   // 20000
  for (int p = 0; p < NPASS; ++p) {
    int lo = p * span;
    int hi = (lo + span < NN) ? lo + span : NN;
    k_scatter<<<EE / 256, 256, 0, stream>>>(src, dst, cursor, csr, lo, hi);
  }

  k_agg    <<<NN / 8, 256, 0, stream>>>(xbf, row_off, csr, nrm, aggb);
  k_gemm   <<<NPAD / 64, 256, 0, stream>>>(aggb, wbf, b1, xbf /* h overwrites xbf */);
  k_pool   <<<GG, 256, 0, stream>>>(xbf, gs, ge, pooled);
  k_out    <<<GG / 4, 256, 0, stream>>>(pooled, W2, b2, out);
}

// Round 4
// 760.155 us; speedup vs baseline: 1.2203x; 1.1207x over previous
//
#include <hip/hip_runtime.h>
#include <cstddef>

#define NN   100000
#define EE   3200000
#define GG   512
#define NPASS 5       // scatter passes; each writes a ~2.6MB L2-resident csr slice

typedef __attribute__((ext_vector_type(8))) short bf16x8;
typedef __attribute__((ext_vector_type(4))) float f32x4;
typedef __attribute__((ext_vector_type(8))) unsigned short u16x8;

static __device__ __forceinline__ unsigned short f2b(float f) {
  unsigned u = __float_as_uint(f);
  unsigned r = u + 0x7fffu + ((u >> 16) & 1u);   // RNE
  return (unsigned short)(r >> 16);
}
static __device__ __forceinline__ float b2f(unsigned short s) {
  return __uint_as_float(((unsigned)s) << 16);
}

// ---------------- degree count (int atomics) ----------------
__global__ void k_deg(const int* __restrict__ src, int* __restrict__ deg) {
  int e = blockIdx.x * 256 + threadIdx.x;
  if (e < EE) atomicAdd(&deg[src[e]], 1);
}

// ---------------- prefix scan (3 stages) ----------------
__global__ void k_scan1(const int* __restrict__ deg, int* __restrict__ bsum) {
  __shared__ int sh[256];
  int i = blockIdx.x * 256 + threadIdx.x;
  int v = (i < NN) ? deg[i] : 0;
  sh[threadIdx.x] = v; __syncthreads();
  for (int s = 128; s > 0; s >>= 1) {
    if (threadIdx.x < s) sh[threadIdx.x] += sh[threadIdx.x + s];
    __syncthreads();
  }
  if (threadIdx.x == 0) bsum[blockIdx.x] = sh[0];
}

__global__ void k_scan2(int* __restrict__ bsum, int nb) {
  __shared__ int sh[512];
  int t = threadIdx.x;
  int v0 = (t < nb) ? bsum[t] : 0;
  sh[t] = v0; __syncthreads();
  for (int s = 1; s < 512; s <<= 1) {
    int a = (t >= s) ? sh[t - s] : 0;
    __syncthreads();
    sh[t] += a;
    __syncthreads();
  }
  if (t < nb) bsum[t] = sh[t] - v0;   // exclusive
}

__global__ void k_scan3(const int* __restrict__ deg, const int* __restrict__ bsum,
                        int* __restrict__ row_off, int* __restrict__ cursor,
                        float* __restrict__ nrm) {
  __shared__ int sh[256];
  int t = threadIdx.x, i = blockIdx.x * 256 + t;
  int v = (i < NN) ? deg[i] : 0;
  sh[t] = v; __syncthreads();
  for (int s = 1; s < 256; s <<= 1) {
    int a = (t >= s) ? sh[t - s] : 0;
    __syncthreads();
    sh[t] += a;
    __syncthreads();
  }
  int excl = sh[t] - v + bsum[blockIdx.x];
  if (i < NN) {
    row_off[i] = excl;
    cursor[i]  = excl;
    nrm[i] = rsqrtf((float)v);        // deg==0 -> +inf, matches deg**-0.5
    if (i == NN - 1) row_off[NN] = excl + v;
  }
}

// ---------------- CSR scatter, src-range partitioned ----------------
__global__ void k_scatter(const int* __restrict__ src, const int* __restrict__ dst,
                          int* __restrict__ cursor, int* __restrict__ csr,
                          int lo, int hi) {
  int e = blockIdx.x * 256 + threadIdx.x;
  if (e < EE) {
    int s = src[e];
    if (s >= lo && s < hi) {
      int slot = atomicAdd(&cursor[s], 1);
      csr[slot] = dst[e];
    }
  }
}

// ---------------- y = norm * x, fp32 -> bf16 ----------------
// agg[i] = n_i * (y_i + sum_d y_d); per-edge work becomes a pure add.
__global__ void k_cvt_y(const float* __restrict__ x, const float* __restrict__ nrm,
                        unsigned short* __restrict__ ybf) {
  int gid = blockIdx.x * 256 + threadIdx.x;   // one float4 per thread; NN*64 total
  int i = gid >> 6;                            // 64 consecutive threads share a node
  float n = nrm[i];
  float4 v = ((const float4*)x)[gid];
  ushort4 o;
  o.x = f2b(n * v.x); o.y = f2b(n * v.y); o.z = f2b(n * v.z); o.w = f2b(n * v.w);
  ((ushort4*)ybf)[gid] = o;
}

__global__ void k_cvt_w(const float* __restrict__ w, unsigned short* __restrict__ wbf) {
  int i = blockIdx.x * 256 + threadIdx.x;   // 16384 quads
  float4 v = ((const float4*)w)[i];
  ushort4 o;
  o.x = f2b(v.x); o.y = f2b(v.y); o.z = f2b(v.z); o.w = f2b(v.w);
  ((ushort4*)wbf)[i] = o;
}

// ---------------- fused: gather-agg -> MFMA GEMM -> relu -> pooled atomicMax ----
// Block = 16 nodes. Phase 1: 8 half-waves gather 2 nodes each (16B/lane),
// scale by n_i, store bf16 rows to LDS (stride 264 = +8 pad, <=2-way banks).
// Phase 2: 4 waves compute the 16x256 h-tile (each wave 64 cols), bias+ReLU,
// in-wave column max, one atomicMax(int) per (graph,col) -- h never hits HBM.
__global__ __launch_bounds__(256) void k_fused(const unsigned short* __restrict__ ybf,
                                               const int* __restrict__ row_off,
                                               const int* __restrict__ csr,
                                               const float* __restrict__ nrm,
                                               const unsigned short* __restrict__ wbf,
                                               const float* __restrict__ b1,
                                               const int* __restrict__ batch,
                                               int* __restrict__ pooled) {
  __shared__ __align__(16) unsigned short As[16][264];
  const int tid  = threadIdx.x;
  const int wave = tid >> 6;
  const int lane = tid & 63;
  const int half = lane >> 5;
  const int l32  = lane & 31;
  const int hw   = wave * 2 + half;       // 8 half-waves
  const int n0   = blockIdx.x * 16;       // 6250 blocks * 16 = 100000 exact

  const u16x8* __restrict__ yr = (const u16x8*)ybf;   // row = 32 x u16x8

  for (int s = 0; s < 2; ++s) {
    const int i  = n0 + hw * 2 + s;
    const int e0 = row_off[i];
    const int e1 = row_off[i + 1];

    u16x8 sv = yr[(size_t)i * 32 + l32];   // self term: y_i
    float acc[8];
#pragma unroll
    for (int c = 0; c < 8; ++c) acc[c] = b2f(sv[c]);

    int e = e0;
    for (; e + 4 <= e1; e += 4) {
      int d0 = csr[e], d1 = csr[e + 1], d2 = csr[e + 2], d3 = csr[e + 3];
      u16x8 v0 = yr[(size_t)d0 * 32 + l32];
      u16x8 v1 = yr[(size_t)d1 * 32 + l32];
      u16x8 v2 = yr[(size_t)d2 * 32 + l32];
      u16x8 v3 = yr[(size_t)d3 * 32 + l32];
#pragma unroll
      for (int c = 0; c < 8; ++c)
        acc[c] += (b2f(v0[c]) + b2f(v1[c])) + (b2f(v2[c]) + b2f(v3[c]));
    }
    for (; e < e1; ++e) {
      int d = csr[e];
      u16x8 v = yr[(size_t)d * 32 + l32];
#pragma unroll
      for (int c = 0; c < 8; ++c) acc[c] += b2f(v[c]);
    }

    const float ni = nrm[i];
    u16x8 o;
#pragma unroll
    for (int c = 0; c < 8; ++c) o[c] = f2b(ni * acc[c]);
    *(u16x8*)&As[hw * 2 + s][l32 * 8] = o;
  }
  __syncthreads();

  // ---- GEMM phase: wave w covers cols [w*64, w*64+64) ----
  const int r16  = lane & 15;
  const int quad = lane >> 4;
  f32x4 acc4[4];
#pragma unroll
  for (int t = 0; t < 4; ++t) acc4[t] = (f32x4){0.f, 0.f, 0.f, 0.f};

  for (int kc = 0; kc < 8; ++kc) {
    bf16x8 af = *(const bf16x8*)&As[r16][kc * 32 + quad * 8];
#pragma unroll
    for (int t = 0; t < 4; ++t) {
      const int n = wave * 64 + t * 16 + r16;
      bf16x8 bf = *(const bf16x8*)(wbf + (size_t)n * 256 + kc * 32 + quad * 8);
      acc4[t] = __builtin_amdgcn_mfma_f32_16x16x32_bf16(af, bf, acc4[t], 0, 0, 0);
    }
  }

  // ---- epilogue: bias + relu + per-graph column max ----
  const int g0 = batch[n0], g15 = batch[n0 + 15];
  if (g0 == g15) {
#pragma unroll
    for (int t = 0; t < 4; ++t) {
      const int col = wave * 64 + t * 16 + r16;
      const float bias = b1[col];
      float m = 0.f;   // relu identity
#pragma unroll
      for (int r = 0; r < 4; ++r) m = fmaxf(m, acc4[t][r] + bias);
      m = fmaxf(m, __shfl_xor(m, 16, 64));
      m = fmaxf(m, __shfl_xor(m, 32, 64));
      if (quad == 0) atomicMax(&pooled[g0 * 256 + col], __float_as_int(m));
    }
  } else {
    // block spans a graph boundary (~8% of blocks): per-row atomics
#pragma unroll
    for (int t = 0; t < 4; ++t) {
      const int col = wave * 64 + t * 16 + r16;
      const float bias = b1[col];
#pragma unroll
      for (int r = 0; r < 4; ++r) {
        const int node = n0 + quad * 4 + r;
        float v = fmaxf(acc4[t][r] + bias, 0.f);
        atomicMax(&pooled[batch[node] * 256 + col], __float_as_int(v));
      }
    }
  }
}

// ---------------- out = pooled @ W2^T + b2 ----------------
__global__ void k_out(const float* __restrict__ pooled, const float* __restrict__ w2,
                      const float* __restrict__ b2, float* __restrict__ out) {
  const int wave = threadIdx.x >> 6;
  const int lane = threadIdx.x & 63;
  const int g = blockIdx.x * 4 + wave;
  float4 p = ((const float4*)pooled)[g * 64 + lane];
  float4 w = ((const float4*)w2)[lane];
  float s = p.x * w.x + p.y * w.y + p.z * w.z + p.w * w.w;
  for (int off = 32; off; off >>= 1) s += __shfl_down(s, off, 64);
  if (lane == 0) out[g] = s + b2[0];
}

extern "C" void kernel_launch(void* const* d_in, const int* in_sizes, int n_in,
                              void* d_out, int out_size, void* d_ws, size_t ws_size,
                              hipStream_t stream) {
  const float* x     = (const float*)d_in[0];
  const int*   ei    = (const int*)d_in[1];
  const int*   batch = (const int*)d_in[2];
  const float* W1    = (const float*)d_in[3];
  const float* b1    = (const float*)d_in[4];
  const float* W2    = (const float*)d_in[5];
  const float* b2    = (const float*)d_in[6];
  const int* src = ei;
  const int* dst = ei + EE;
  float* out = (float*)d_out;

  // workspace carve (256B aligned)
  size_t off = 0;
  auto carve = [&](size_t bytes) -> void* {
    void* p = (char*)d_ws + off;
    off += (bytes + 255) & ~(size_t)255;
    return p;
  };
  unsigned short* ybf  = (unsigned short*)carve((size_t)NN * 256 * 2);
  int*   csr     = (int*)carve((size_t)EE * 4);
  int*   deg     = (int*)carve((size_t)NN * 4);
  int*   row_off = (int*)carve((size_t)(NN + 1) * 4);
  int*   cursor  = (int*)carve((size_t)NN * 4);
  float* nrm     = (float*)carve((size_t)NN * 4);
  int*   bsum    = (int*)carve(512 * 4);
  int*   pooled  = (int*)carve((size_t)GG * 256 * 4);   // fp32 bit patterns
  unsigned short* wbf = (unsigned short*)carve(256 * 256 * 2);

  const int NB = (NN + 255) / 256;   // 391

  hipMemsetAsync(deg, 0, (size_t)NN * 4, stream);
  hipMemsetAsync(pooled, 0, (size_t)GG * 256 * 4, stream);   // 0 == 0.0f, relu floor

  k_deg    <<<EE / 256, 256, 0, stream>>>(src, deg);
  k_scan1  <<<NB, 256, 0, stream>>>(deg, bsum);
  k_scan2  <<<1, 512, 0, stream>>>(bsum, NB);
  k_scan3  <<<NB, 256, 0, stream>>>(deg, bsum, row_off, cursor, nrm);
  k_cvt_y  <<<NN * 64 / 256, 256, 0, stream>>>(x, nrm, ybf);
  k_cvt_w  <<<64, 256, 0, stream>>>(W1, wbf);

  // src-range passes: each pass's csr slice (~2.6MB) stays L2-resident so the
  // 16 slot-writes per 64B line coalesce before writeback.
  const int span = (NN + NPASS - 1) / NPASS;   // 20000
  for (int p = 0; p < NPASS; ++p) {
    int lo = p * span;
    int hi = (lo + span < NN) ? lo + span : NN;
    k_scatter<<<EE / 256, 256, 0, stream>>>(src, dst, cursor, csr, lo, hi);
  }

  k_fused  <<<NN / 16, 256, 0, stream>>>(ybf, row_off, csr, nrm, wbf, b1, batch, pooled);
  k_out    <<<GG / 4, 256, 0, stream>>>((const float*)pooled, W2, b2, out);
}

// Round 5
// 571.598 us; speedup vs baseline: 1.6228x; 1.3299x over previous
//
#include <hip/hip_runtime.h>
#include <cstddef>

#define NN   100000
#define EE   3200000
#define GG   512
#define NBKT 1563          // ceil(NN/64) buckets of 64 nodes
#define CAP  2432          // bucket capacity: mean 2048, +8.5 sigma

typedef __attribute__((ext_vector_type(8))) short bf16x8;
typedef __attribute__((ext_vector_type(4))) float f32x4;
typedef __attribute__((ext_vector_type(8))) unsigned short u16x8;

static __device__ __forceinline__ unsigned short f2b(float f) {
  unsigned u = __float_as_uint(f);
  unsigned r = u + 0x7fffu + ((u >> 16) & 1u);   // RNE
  return (unsigned short)(r >> 16);
}
static __device__ __forceinline__ float b2f(unsigned short s) {
  return __uint_as_float(((unsigned)s) << 16);
}

// ---------------- bucket scatter: edges -> 64-node buckets ----------------
// LDS-staged: per-block LDS histogram, ONE global atomicAdd per (block,bin)
// to reserve a range, then LDS-cursor placement. Packed word = src_local<<17 | dst.
__global__ __launch_bounds__(1024) void k_bscatter(const int* __restrict__ src,
                                                   const int* __restrict__ dst,
                                                   int* __restrict__ gcur,
                                                   int* __restrict__ pk) {
  __shared__ int cnt[NBKT];
  __shared__ int base[NBKT];
  const int tid  = threadIdx.x;
  const int e_lo = blockIdx.x * (EE / 128);   // 128 blocks x 25000 edges
  const int e_hi = e_lo + (EE / 128);

  for (int b = tid; b < NBKT; b += 1024) cnt[b] = 0;
  __syncthreads();
  for (int e = e_lo + tid; e < e_hi; e += 1024)
    atomicAdd(&cnt[src[e] >> 6], 1);
  __syncthreads();
  for (int b = tid; b < NBKT; b += 1024) {
    int c = cnt[b];
    base[b] = c ? atomicAdd(&gcur[b], c) : 0;
    cnt[b] = 0;
  }
  __syncthreads();
  for (int e = e_lo + tid; e < e_hi; e += 1024) {
    int s = src[e];
    int b = s >> 6;
    int idx = base[b] + atomicAdd(&cnt[b], 1);
    if (idx < CAP) pk[b * CAP + idx] = ((s & 63) << 17) | dst[e];
  }
}

// ---------------- per-bucket degree -> y = deg^-1/2 * x (bf16); + W1 cvt ----
__global__ __launch_bounds__(512) void k_nrmy(const int* __restrict__ gcur,
                                              const int* __restrict__ pk,
                                              const float* __restrict__ x,
                                              const float* __restrict__ w1,
                                              unsigned short* __restrict__ ybf,
                                              unsigned short* __restrict__ wbf) {
  __shared__ int hist[64];
  const int tid = threadIdx.x;
  const int b   = blockIdx.x;
  const int n0  = b * 64;

  if (tid < 64) hist[tid] = 0;
  __syncthreads();
  const int szc = min(gcur[b], CAP);
  for (int j = tid; j < szc; j += 512)
    atomicAdd(&hist[pk[b * CAP + j] >> 17], 1);
  __syncthreads();

  for (int it = 0; it < 8; ++it) {
    int idx = it * 512 + tid;          // 0..4095 = 64 rows x 64 float4
    int row = idx >> 6, c4 = idx & 63;
    int n = n0 + row;
    if (n < NN) {
      float nr = rsqrtf((float)hist[row]);
      float4 v = ((const float4*)x)[(size_t)n * 64 + c4];
      ushort4 o;
      o.x = f2b(nr * v.x); o.y = f2b(nr * v.y); o.z = f2b(nr * v.z); o.w = f2b(nr * v.w);
      ((ushort4*)ybf)[(size_t)n * 64 + c4] = o;
    }
  }
  if (b < 64 && tid < 256) {           // W1 -> bf16, 64 blocks x 256 float4
    int i = b * 256 + tid;
    float4 v = ((const float4*)w1)[i];
    ushort4 o;
    o.x = f2b(v.x); o.y = f2b(v.y); o.z = f2b(v.z); o.w = f2b(v.w);
    ((ushort4*)wbf)[i] = o;
  }
}

// ---------------- fused: LDS sort -> gather-agg -> MFMA -> relu -> pool ------
// Block = one 64-node bucket, 512 threads (8 waves), 3 blocks/CU (44.5KB LDS).
__global__ __launch_bounds__(512, 6) void k_fused2(const int* __restrict__ gcur,
                                                   const int* __restrict__ pk,
                                                   const unsigned short* __restrict__ ybf,
                                                   const unsigned short* __restrict__ wbf,
                                                   const float* __restrict__ b1,
                                                   const int* __restrict__ batch,
                                                   int* __restrict__ pooled) {
  __shared__ int hist[64], start[64], cur[64], bg[64];
  __shared__ int sorted[CAP];
  __shared__ __align__(16) unsigned short As[64][264];
  const int tid  = threadIdx.x;
  const int b    = blockIdx.x;
  const int n0   = b * 64;
  const int wave = tid >> 6;
  const int lane = tid & 63;

  // ---- counting sort of bucket edges by src_local (all in LDS) ----
  if (tid < 64) { hist[tid] = 0; bg[tid] = batch[min(n0 + tid, NN - 1)]; }
  __syncthreads();
  const int szc = min(gcur[b], CAP);
  for (int j = tid; j < szc; j += 512)
    atomicAdd(&hist[pk[b * CAP + j] >> 17], 1);
  __syncthreads();
  if (tid < 64) {
    int s = 0;
    for (int t = 0; t < tid; ++t) s += hist[t];
    start[tid] = s; cur[tid] = s;
  }
  __syncthreads();
  for (int j = tid; j < szc; j += 512) {
    int w = pk[b * CAP + j];
    int pos = atomicAdd(&cur[w >> 17], 1);
    sorted[pos] = w & 0x1FFFF;
  }
  __syncthreads();

  // ---- gather phase: half-wave per node, 4 nodes each ----
  const int half = lane >> 5, l32 = lane & 31;
  const int hw   = wave * 2 + half;   // 16 half-waves
  const u16x8* __restrict__ yr = (const u16x8*)ybf;   // row = 32 x u16x8
  for (int s = 0; s < 4; ++s) {
    const int il = hw * 4 + s;
    const int i  = n0 + il;
    u16x8 o;
    if (i < NN) {
      u16x8 sv = yr[(size_t)i * 32 + l32];   // self term y_i
      float acc[8];
#pragma unroll
      for (int c = 0; c < 8; ++c) acc[c] = b2f(sv[c]);
      int e  = start[il];
      const int e1 = start[il] + hist[il];
      for (; e + 4 <= e1; e += 4) {
        int d0 = sorted[e], d1 = sorted[e + 1], d2 = sorted[e + 2], d3 = sorted[e + 3];
        u16x8 v0 = yr[(size_t)d0 * 32 + l32];
        u16x8 v1 = yr[(size_t)d1 * 32 + l32];
        u16x8 v2 = yr[(size_t)d2 * 32 + l32];
        u16x8 v3 = yr[(size_t)d3 * 32 + l32];
#pragma unroll
        for (int c = 0; c < 8; ++c)
          acc[c] += (b2f(v0[c]) + b2f(v1[c])) + (b2f(v2[c]) + b2f(v3[c]));
      }
      for (; e < e1; ++e) {
        u16x8 v = yr[(size_t)sorted[e] * 32 + l32];
#pragma unroll
        for (int c = 0; c < 8; ++c) acc[c] += b2f(v[c]);
      }
      const float ni = rsqrtf((float)hist[il]);
#pragma unroll
      for (int c = 0; c < 8; ++c) o[c] = f2b(ni * acc[c]);
    } else {
#pragma unroll
      for (int c = 0; c < 8; ++c) o[c] = 0;
    }
    *(u16x8*)&As[il][l32 * 8] = o;
  }
  __syncthreads();

  // ---- MFMA phase: wave -> row-tile rt = wave&3, col-group cg = wave>>2 ----
  const int r16 = lane & 15, quad = lane >> 4;
  const int rt = wave & 3, cg = wave >> 2;
  f32x4 acc4[8];
#pragma unroll
  for (int t = 0; t < 8; ++t) acc4[t] = (f32x4){0.f, 0.f, 0.f, 0.f};
  for (int kc = 0; kc < 8; ++kc) {
    bf16x8 af = *(const bf16x8*)&As[rt * 16 + r16][kc * 32 + quad * 8];
#pragma unroll
    for (int ct = 0; ct < 8; ++ct) {
      const int n = cg * 128 + ct * 16 + r16;
      bf16x8 bf = *(const bf16x8*)(wbf + (size_t)n * 256 + kc * 32 + quad * 8);
      acc4[ct] = __builtin_amdgcn_mfma_f32_16x16x32_bf16(af, bf, acc4[ct], 0, 0, 0);
    }
  }

  // ---- epilogue: bias + relu + segmented column max + atomicMax ----
  const int row0 = rt * 16;
  const int g_lo = bg[row0], g_hi = bg[row0 + 15];
#pragma unroll
  for (int ct = 0; ct < 8; ++ct) {
    const int col = cg * 128 + ct * 16 + r16;
    const float bias = b1[col];
    float v[4];
#pragma unroll
    for (int r = 0; r < 4; ++r) v[r] = fmaxf(acc4[ct][r] + bias, 0.f);
    for (int g = g_lo; g <= g_hi; ++g) {
      float m = 0.f;
#pragma unroll
      for (int r = 0; r < 4; ++r) {
        const int row = row0 + quad * 4 + r;
        if (bg[row] == g && n0 + row < NN) m = fmaxf(m, v[r]);
      }
      m = fmaxf(m, __shfl_xor(m, 16, 64));
      m = fmaxf(m, __shfl_xor(m, 32, 64));
      if (quad == 0) atomicMax(&pooled[g * 256 + col], __float_as_int(m));
    }
  }
}

// ---------------- out = pooled @ W2^T + b2 ----------------
__global__ void k_out(const float* __restrict__ pooled, const float* __restrict__ w2,
                      const float* __restrict__ b2, float* __restrict__ out) {
  const int wave = threadIdx.x >> 6;
  const int lane = threadIdx.x & 63;
  const int g = blockIdx.x * 4 + wave;
  float4 p = ((const float4*)pooled)[g * 64 + lane];
  float4 w = ((const float4*)w2)[lane];
  float s = p.x * w.x + p.y * w.y + p.z * w.z + p.w * w.w;
  for (int off = 32; off; off >>= 1) s += __shfl_down(s, off, 64);
  if (lane == 0) out[g] = s + b2[0];
}

extern "C" void kernel_launch(void* const* d_in, const int* in_sizes, int n_in,
                              void* d_out, int out_size, void* d_ws, size_t ws_size,
                              hipStream_t stream) {
  const float* x     = (const float*)d_in[0];
  const int*   ei    = (const int*)d_in[1];
  const int*   batch = (const int*)d_in[2];
  const float* W1    = (const float*)d_in[3];
  const float* b1    = (const float*)d_in[4];
  const float* W2    = (const float*)d_in[5];
  const float* b2    = (const float*)d_in[6];
  const int* src = ei;
  const int* dst = ei + EE;
  float* out = (float*)d_out;

  // workspace carve (256B aligned)
  size_t off = 0;
  auto carve = [&](size_t bytes) -> void* {
    void* p = (char*)d_ws + off;
    off += (bytes + 255) & ~(size_t)255;
    return p;
  };
  int*   pooled = (int*)carve((size_t)GG * 256 * 4);      // fp32 bit patterns
  int*   gcur   = (int*)carve((size_t)NBKT * 4);          // adjacent: one memset
  unsigned short* ybf = (unsigned short*)carve((size_t)NN * 256 * 2);
  int*   pk     = (int*)carve((size_t)NBKT * CAP * 4);    // packed bucket edges
  unsigned short* wbf = (unsigned short*)carve(256 * 256 * 2);

  // zero pooled (relu floor) + gcur in one shot (contiguous carves)
  hipMemsetAsync(pooled, 0, (size_t)GG * 256 * 4 + (size_t)NBKT * 4, stream);

  k_bscatter<<<128,  1024, 0, stream>>>(src, dst, gcur, pk);
  k_nrmy    <<<NBKT,  512, 0, stream>>>(gcur, pk, x, W1, ybf, wbf);
  k_fused2  <<<NBKT,  512, 0, stream>>>(gcur, pk, ybf, wbf, b1, batch, pooled);
  k_out     <<<GG / 4, 256, 0, stream>>>((const float*)pooled, W2, b2, out);
}